// Round 1
// baseline (289.096 us; speedup 1.0000x reference)
//
#include <hip/hip_runtime.h>
#include <stdint.h>

#define OUT_F   4096
#define IN_F    11008
#define BATCH   64
#define NSPLIT  8
#define KC      (IN_F / NSPLIT)    // 1376
#define STEPS   (KC / 32)          // 43 sub-blocks per K-split
#define IPR     (IN_F / 2)         // 5504 ints per weight row
#define SB_ROW  (IN_F / 32)        // 344 sub-blocks per row
#define SUP_ROW (IN_F / 256)       // 43 super-blocks per row

typedef __attribute__((ext_vector_type(8))) short  short8;
typedef __attribute__((ext_vector_type(4))) float  floatx4;
typedef __attribute__((ext_vector_type(4))) int    intx4;

__global__ __launch_bounds__(256) void init_out_kernel(const float* __restrict__ bias,
                                                       float* __restrict__ out) {
    int i = blockIdx.x * 256 + threadIdx.x;
    out[i] = bias[i & (OUT_F - 1)];
}

// pack two fp32 into two truncated bf16 in one v_perm
__device__ __forceinline__ unsigned pack_bf16(float f0, float f1) {
    return __builtin_amdgcn_perm(__float_as_uint(f1), __float_as_uint(f0), 0x07060302u);
}

__global__ __launch_bounds__(256, 2) void qlin_kernel(
    const float* __restrict__ x,
    const int*   __restrict__ packed,
    const float* __restrict__ dd,
    const float* __restrict__ dmn_g,
    const int*   __restrict__ scales,
    const int*   __restrict__ mins,
    float*       __restrict__ out)
{
    const int bid = blockIdx.x;
    const int ks  = bid >> 6;          // K-split 0..7
    const int nb  = bid & 63;          // output-column block 0..63
    const int wv  = threadIdx.x >> 6;  // M-tile 0..3
    const int ln  = threadIdx.x & 63;
    const int lo  = ln & 15;
    const int hi  = ln >> 4;           // k-quad 0..3

    // A operand: x[m][k], m = wv*16+lo, k = ks*KC + step*32 + hi*8 + j
    const int m = wv * 16 + lo;
    const float* aptr = x + (m * IN_F + ks * KC + hi * 8);

    const int* bptr[4];
    int scbase[4];
    int obase[4];
    #pragma unroll
    for (int nt = 0; nt < 4; ++nt) {
        int o = nb * 64 + nt * 16 + lo;           // weight row (output feature)
        obase[nt]  = o;
        bptr[nt]   = packed + (o * IPR + ks * (KC / 2) + hi * 4);
        scbase[nt] = o * SB_ROW + ks * STEPS;     // linear sub-block index
    }

    floatx4 acc[4];
    #pragma unroll
    for (int nt = 0; nt < 4; ++nt) acc[nt] = (floatx4)0.0f;

    float dk[4], dm[4], dmn[4];

    #pragma unroll 1
    for (int step = 0; step < STEPS; ++step) {
        const int sbs = ks * STEPS + step;        // sub-block index within row

        // ---- issue all loads ----
        floatx4 a0 = *(const floatx4*)(aptr);
        floatx4 a1 = *(const floatx4*)(aptr + 4);
        aptr += 32;

        intx4 braw[4];
        int scv[4], mnv[4];
        #pragma unroll
        for (int nt = 0; nt < 4; ++nt) {
            braw[nt] = *(const intx4*)bptr[nt];   // 4 ints = 8 quants, one sub-block
            bptr[nt] += 16;                        // advance 32 quants
            scv[nt] = scales[scbase[nt] + step];
            mnv[nt] = mins[scbase[nt] + step];
        }

        // super-block constants (d, dmin) change every 8 sub-blocks
        if ((sbs & 7) == 0 || step == 0) {
            #pragma unroll
            for (int nt = 0; nt < 4; ++nt) {
                int s = obase[nt] * SUP_ROW + (sbs >> 3);
                float dv = dd[s];
                dk[nt]  = dv * (1.0f / 945.0f);   // d/(63*15)
                dm[nt]  = dv * (1.0f / 63.0f);
                dmn[nt] = dmn_g[s];
            }
        }

        // ---- A fragment: 8 fp32 -> 8 bf16 ----
        union { intx4 i; short8 s; } ua;
        ua.i.x = pack_bf16(a0.x, a0.y);
        ua.i.y = pack_bf16(a0.z, a0.w);
        ua.i.z = pack_bf16(a1.x, a1.y);
        ua.i.w = pack_bf16(a1.z, a1.w);
        short8 af = ua.s;

        // ---- B fragments: dequant + MFMA ----
        #pragma unroll
        for (int nt = 0; nt < 4; ++nt) {
            float A = dk[nt] * (float)scv[nt];
            float B = fmaf(dm[nt], (float)mnv[nt], dmn[nt]);
            union { intx4 i; short8 s; } uw;
            int v;
            float w0, w1;
            v = braw[nt].x;
            w0 = fmaf((float)(v & 15), A, B);
            w1 = fmaf((float)((v >> 4) & 15), A, B);
            uw.i.x = pack_bf16(w0, w1);
            v = braw[nt].y;
            w0 = fmaf((float)(v & 15), A, B);
            w1 = fmaf((float)((v >> 4) & 15), A, B);
            uw.i.y = pack_bf16(w0, w1);
            v = braw[nt].z;
            w0 = fmaf((float)(v & 15), A, B);
            w1 = fmaf((float)((v >> 4) & 15), A, B);
            uw.i.z = pack_bf16(w0, w1);
            v = braw[nt].w;
            w0 = fmaf((float)(v & 15), A, B);
            w1 = fmaf((float)((v >> 4) & 15), A, B);
            uw.i.w = pack_bf16(w0, w1);

            acc[nt] = __builtin_amdgcn_mfma_f32_16x16x32_bf16(af, uw.s, acc[nt], 0, 0, 0);
        }
    }

    // ---- epilogue: C/D layout col=lane&15 (N), row=(lane>>4)*4+reg (M) ----
    #pragma unroll
    for (int nt = 0; nt < 4; ++nt) {
        int col = nb * 64 + nt * 16 + lo;
        #pragma unroll
        for (int r = 0; r < 4; ++r) {
            int row = wv * 16 + hi * 4 + r;
            atomicAdd(out + row * OUT_F + col, acc[nt][r]);
        }
    }
}

extern "C" void kernel_launch(void* const* d_in, const int* in_sizes, int n_in,
                              void* d_out, int out_size, void* d_ws, size_t ws_size,
                              hipStream_t stream) {
    (void)in_sizes; (void)n_in; (void)d_ws; (void)ws_size; (void)out_size;
    const float* x      = (const float*)d_in[0];
    const int*   packed = (const int*)d_in[1];
    const float* d      = (const float*)d_in[2];
    const float* dmin   = (const float*)d_in[3];
    const int*   scales = (const int*)d_in[4];
    const int*   mins   = (const int*)d_in[5];
    const float* bias   = (const float*)d_in[6];
    float* out = (float*)d_out;

    init_out_kernel<<<(BATCH * OUT_F) / 256, 256, 0, stream>>>(bias, out);
    qlin_kernel<<<NSPLIT * (OUT_F / 64), 256, 0, stream>>>(x, packed, d, dmin, scales, mins, out);
}